// Round 1
// baseline (5928.492 us; speedup 1.0000x reference)
//
#include <hip/hip_runtime.h>
#include <math.h>

#define HH 128
#define RR 16
#define W2S 132   // padded LDS row stride (16B-aligned rows, breaks write bank conflicts)

__global__ __launch_bounds__(256, 1)
void siren_fused(const float* __restrict__ pos,
                 const float* __restrict__ grid,
                 const float* __restrict__ W1, const float* __restrict__ b1,
                 const float* __restrict__ W2, const float* __restrict__ b2,
                 const float* __restrict__ W3, const float* __restrict__ b3,
                 float* __restrict__ out, int N)
{
    __shared__ float sW2[HH * W2S];  // sW2[i*W2S + j] = W2[j][i]  (transposed)
    __shared__ float sW1[HH * 8];    // sW1[j*8+k]: k<5 -> W1[k][j], k==5 -> b1[j]
    __shared__ float sb2[HH];
    __shared__ float sW3[HH];

    const int tid = threadIdx.x;

    // ---- cooperative staging of weights into LDS ----
    for (int idx = tid; idx < HH * HH; idx += 256) {
        const int j = idx >> 7;          // W2 row (input dim)
        const int i = idx & (HH - 1);    // W2 col (output dim)
        sW2[i * W2S + j] = W2[idx];      // coalesced global read, transposed LDS write
    }
    if (tid < HH) {
        sb2[tid] = b2[tid];
        sW3[tid] = W3[tid];
        #pragma unroll
        for (int k = 0; k < 5; ++k) sW1[tid * 8 + k] = W1[k * HH + tid];
        sW1[tid * 8 + 5] = b1[tid];
        sW1[tid * 8 + 6] = 0.f;
        sW1[tid * 8 + 7] = 0.f;
    }
    const float b3v = b3[0];
    __syncthreads();

    const int p = blockIdx.x * 256 + tid;
    if (p >= N) return;

    const float px = pos[p * 3 + 0];
    const float py = pos[p * 3 + 1];
    const float pz = pos[p * 3 + 2];

    // ---- trilerp forward ----
    const float ux = (px + 1.f) * 7.5f;
    const float uy = (py + 1.f) * 7.5f;
    const float uz = (pz + 1.f) * 7.5f;
    int ix = (int)floorf(ux); ix = ix < 0 ? 0 : (ix > RR - 2 ? RR - 2 : ix);
    int iy = (int)floorf(uy); iy = iy < 0 ? 0 : (iy > RR - 2 ? RR - 2 : iy);
    int iz = (int)floorf(uz); iz = iz < 0 ? 0 : (iz > RR - 2 ? RR - 2 : iz);
    const float fx = ux - (float)ix;
    const float fy = uy - (float)iy;
    const float fz = uz - (float)iz;

    const float2* __restrict__ g2 = (const float2*)grid;
    const int cbase = (ix * RR + iy) * RR + iz;

    float e0, e1;
    {
        const float2 c000 = g2[cbase];
        const float2 c001 = g2[cbase + 1];
        const float2 c010 = g2[cbase + RR];
        const float2 c011 = g2[cbase + RR + 1];
        const float2 c100 = g2[cbase + RR * RR];
        const float2 c101 = g2[cbase + RR * RR + 1];
        const float2 c110 = g2[cbase + RR * RR + RR];
        const float2 c111 = g2[cbase + RR * RR + RR + 1];
        const float wx0 = 1.f - fx, wx1 = fx;
        const float wy0 = 1.f - fy, wy1 = fy;
        const float wz0 = 1.f - fz, wz1 = fz;
        const float w000 = wx0 * wy0 * wz0, w001 = wx0 * wy0 * wz1;
        const float w010 = wx0 * wy1 * wz0, w011 = wx0 * wy1 * wz1;
        const float w100 = wx1 * wy0 * wz0, w101 = wx1 * wy0 * wz1;
        const float w110 = wx1 * wy1 * wz0, w111 = wx1 * wy1 * wz1;
        e0 = w000 * c000.x + w001 * c001.x + w010 * c010.x + w011 * c011.x
           + w100 * c100.x + w101 * c101.x + w110 * c110.x + w111 * c111.x;
        e1 = w000 * c000.y + w001 * c001.y + w010 * c010.y + w011 * c011.y
           + w100 * c100.y + w101 * c101.y + w110 * c110.y + w111 * c111.y;
    }

    const float x0 = e0, x1 = e1, x2 = px, x3 = py, x4 = pz;

    // ---- layer 1: h1 = sin(30*(x@W1+b1)) ----
    float h1v[HH];
    #pragma unroll
    for (int j = 0; j < HH; ++j) {
        const float4 wa = *(const float4*)(&sW1[j * 8]);
        const float2 wb = *(const float2*)(&sW1[j * 8 + 4]);
        float z = wb.y;
        z = fmaf(x0, wa.x, z);
        z = fmaf(x1, wa.y, z);
        z = fmaf(x2, wa.z, z);
        z = fmaf(x3, wa.w, z);
        z = fmaf(x4, wb.x, z);
        h1v[j] = __sinf(30.f * z);
    }

    // ---- fused layer2 fwd + head + layer2 bwd ----
    // z2_i = b2_i + sum_j h1_j * W2[j][i]   (row i of transposed sW2)
    // sdf += sin(z2_i)*W3_i ; t_i = W3_i*cos(z2_i)
    // u_j += t_i * W2[j][i]                 (same row, reused)
    float uacc[HH];
    #pragma unroll
    for (int j = 0; j < HH; ++j) uacc[j] = 0.f;
    float sdf = b3v;

    for (int i = 0; i < HH; ++i) {
        const float* __restrict__ wrow = &sW2[i * W2S];
        float a0 = 0.f, a1 = 0.f, a2 = 0.f, a3 = 0.f;
        #pragma unroll
        for (int j = 0; j < HH; j += 4) {
            const float4 w = *(const float4*)(&wrow[j]);
            a0 = fmaf(h1v[j + 0], w.x, a0);
            a1 = fmaf(h1v[j + 1], w.y, a1);
            a2 = fmaf(h1v[j + 2], w.z, a2);
            a3 = fmaf(h1v[j + 3], w.w, a3);
        }
        const float z2 = sb2[i] + ((a0 + a1) + (a2 + a3));
        const float s = __sinf(z2);
        const float c = __cosf(z2);
        const float w3i = sW3[i];
        sdf = fmaf(s, w3i, sdf);
        const float ti = w3i * c;
        #pragma unroll
        for (int j = 0; j < HH; j += 4) {
            const float4 w = *(const float4*)(&wrow[j]);
            uacc[j + 0] = fmaf(ti, w.x, uacc[j + 0]);
            uacc[j + 1] = fmaf(ti, w.y, uacc[j + 1]);
            uacc[j + 2] = fmaf(ti, w.z, uacc[j + 2]);
            uacc[j + 3] = fmaf(ti, w.w, uacc[j + 3]);
        }
    }

    // ---- backward through layer 1 (recompute z1) ----
    // s_j = u_j * 30 * cos(30*z1_j);  dx_k = sum_j W1[k][j] * s_j
    float d0 = 0.f, d1 = 0.f, d2 = 0.f, d3 = 0.f, d4 = 0.f;
    #pragma unroll
    for (int j = 0; j < HH; ++j) {
        const float4 wa = *(const float4*)(&sW1[j * 8]);
        const float2 wb = *(const float2*)(&sW1[j * 8 + 4]);
        float z = wb.y;
        z = fmaf(x0, wa.x, z);
        z = fmaf(x1, wa.y, z);
        z = fmaf(x2, wa.z, z);
        z = fmaf(x3, wa.w, z);
        z = fmaf(x4, wb.x, z);
        const float sj = uacc[j] * 30.f * __cosf(30.f * z);
        d0 = fmaf(sj, wa.x, d0);
        d1 = fmaf(sj, wa.y, d1);
        d2 = fmaf(sj, wa.z, d2);
        d3 = fmaf(sj, wa.w, d3);
        d4 = fmaf(sj, wb.x, d4);
    }

    // ---- trilerp backward: grad_p += (dw/dp) . (corner . d_emb) ----
    const float de0 = d0, de1 = d1;
    float gx, gy, gz;
    {
        const float2 r000 = g2[cbase];
        const float2 r001 = g2[cbase + 1];
        const float2 r010 = g2[cbase + RR];
        const float2 r011 = g2[cbase + RR + 1];
        const float2 r100 = g2[cbase + RR * RR];
        const float2 r101 = g2[cbase + RR * RR + 1];
        const float2 r110 = g2[cbase + RR * RR + RR];
        const float2 r111 = g2[cbase + RR * RR + RR + 1];
        const float q000 = r000.x * de0 + r000.y * de1;
        const float q001 = r001.x * de0 + r001.y * de1;
        const float q010 = r010.x * de0 + r010.y * de1;
        const float q011 = r011.x * de0 + r011.y * de1;
        const float q100 = r100.x * de0 + r100.y * de1;
        const float q101 = r101.x * de0 + r101.y * de1;
        const float q110 = r110.x * de0 + r110.y * de1;
        const float q111 = r111.x * de0 + r111.y * de1;
        const float wx0 = 1.f - fx, wx1 = fx;
        const float wy0 = 1.f - fy, wy1 = fy;
        const float wz0 = 1.f - fz, wz1 = fz;
        gx = 7.5f * (wy0 * wz0 * (q100 - q000) + wy0 * wz1 * (q101 - q001)
                   + wy1 * wz0 * (q110 - q010) + wy1 * wz1 * (q111 - q011));
        gy = 7.5f * (wx0 * wz0 * (q010 - q000) + wx0 * wz1 * (q011 - q001)
                   + wx1 * wz0 * (q110 - q100) + wx1 * wz1 * (q111 - q101));
        gz = 7.5f * (wx0 * wy0 * (q001 - q000) + wx0 * wy1 * (q011 - q010)
                   + wx1 * wy0 * (q101 - q100) + wx1 * wy1 * (q111 - q110));
    }

    const bool m = (px >= -1.f) && (px <= 1.f) && (py >= -1.f) && (py <= 1.f)
                && (pz >= -1.f) && (pz <= 1.f);

    // ---- outputs: sdf (N), grad (N,3), mask (N) ----
    out[p] = sdf;
    out[N + 3 * p + 0] = d2 + gx;
    out[N + 3 * p + 1] = d3 + gy;
    out[N + 3 * p + 2] = d4 + gz;
    out[4 * N + p] = m ? 1.f : 0.f;
}

extern "C" void kernel_launch(void* const* d_in, const int* in_sizes, int n_in,
                              void* d_out, int out_size, void* d_ws, size_t ws_size,
                              hipStream_t stream) {
    const float* pos  = (const float*)d_in[0];
    const float* grid = (const float*)d_in[1];
    const float* W1   = (const float*)d_in[2];
    const float* b1   = (const float*)d_in[3];
    const float* W2   = (const float*)d_in[4];
    const float* b2   = (const float*)d_in[5];
    const float* W3   = (const float*)d_in[6];
    const float* b3   = (const float*)d_in[7];
    float* out = (float*)d_out;
    const int N = in_sizes[0] / 3;
    const int blocks = (N + 255) / 256;
    hipLaunchKernelGGL(siren_fused, dim3(blocks), dim3(256), 0, stream,
                       pos, grid, W1, b1, W2, b2, W3, b3, out, N);
}

// Round 2
// 2168.349 us; speedup vs baseline: 2.7341x; 2.7341x over previous
//
#include <hip/hip_runtime.h>
#include <math.h>

#define HH 128
#define RR 16

__global__ __launch_bounds__(256, 2)
void siren_fused(const float* __restrict__ pos,
                 const float* __restrict__ grid,
                 const float* __restrict__ W1, const float* __restrict__ b1,
                 const float* __restrict__ W2, const float* __restrict__ b2,
                 const float* __restrict__ W3, const float* __restrict__ b3,
                 float* __restrict__ out, int N)
{
    __shared__ float sW2[HH * HH];  // row-major: sW2[j*HH + i] = W2[j][i]
    __shared__ float sW1[HH * 8];   // sW1[j*8+k]: k<5 -> W1[k][j], k==5 -> b1[j]
    __shared__ float sb2[HH];
    __shared__ float sW3[HH];

    const int tid = threadIdx.x;

    // ---- cooperative staging (coalesced, no transpose, no conflicts) ----
    {
        const float4* __restrict__ W2v = (const float4*)W2;
        float4* sW2v = (float4*)sW2;
        #pragma unroll
        for (int it = 0; it < (HH * HH / 4) / 256; ++it)
            sW2v[it * 256 + tid] = W2v[it * 256 + tid];
    }
    if (tid < HH) {
        sb2[tid] = b2[tid];
        sW3[tid] = W3[tid];
        #pragma unroll
        for (int k = 0; k < 5; ++k) sW1[tid * 8 + k] = W1[k * HH + tid];
        sW1[tid * 8 + 5] = b1[tid];
        sW1[tid * 8 + 6] = 0.f;
        sW1[tid * 8 + 7] = 0.f;
    }
    const float b3v = b3[0];
    __syncthreads();

    const int p = blockIdx.x * 256 + tid;
    if (p >= N) return;

    const float px = pos[p * 3 + 0];
    const float py = pos[p * 3 + 1];
    const float pz = pos[p * 3 + 2];

    // ---- trilerp forward ----
    const float ux = (px + 1.f) * 7.5f;
    const float uy = (py + 1.f) * 7.5f;
    const float uz = (pz + 1.f) * 7.5f;
    int ix = (int)floorf(ux); ix = ix < 0 ? 0 : (ix > RR - 2 ? RR - 2 : ix);
    int iy = (int)floorf(uy); iy = iy < 0 ? 0 : (iy > RR - 2 ? RR - 2 : iy);
    int iz = (int)floorf(uz); iz = iz < 0 ? 0 : (iz > RR - 2 ? RR - 2 : iz);
    const float fx = ux - (float)ix;
    const float fy = uy - (float)iy;
    const float fz = uz - (float)iz;

    const float2* __restrict__ g2 = (const float2*)grid;
    const int cbase = (ix * RR + iy) * RR + iz;

    float e0, e1;
    float wx0, wx1, wy0, wy1, wz0, wz1;
    {
        const float2 c000 = g2[cbase];
        const float2 c001 = g2[cbase + 1];
        const float2 c010 = g2[cbase + RR];
        const float2 c011 = g2[cbase + RR + 1];
        const float2 c100 = g2[cbase + RR * RR];
        const float2 c101 = g2[cbase + RR * RR + 1];
        const float2 c110 = g2[cbase + RR * RR + RR];
        const float2 c111 = g2[cbase + RR * RR + RR + 1];
        wx0 = 1.f - fx; wx1 = fx;
        wy0 = 1.f - fy; wy1 = fy;
        wz0 = 1.f - fz; wz1 = fz;
        const float w000 = wx0 * wy0 * wz0, w001 = wx0 * wy0 * wz1;
        const float w010 = wx0 * wy1 * wz0, w011 = wx0 * wy1 * wz1;
        const float w100 = wx1 * wy0 * wz0, w101 = wx1 * wy0 * wz1;
        const float w110 = wx1 * wy1 * wz0, w111 = wx1 * wy1 * wz1;
        e0 = w000 * c000.x + w001 * c001.x + w010 * c010.x + w011 * c011.x
           + w100 * c100.x + w101 * c101.x + w110 * c110.x + w111 * c111.x;
        e1 = w000 * c000.y + w001 * c001.y + w010 * c010.y + w011 * c011.y
           + w100 * c100.y + w101 * c101.y + w110 * c110.y + w111 * c111.y;
    }

    const float x0 = e0, x1 = e1, x2 = px, x3 = py, x4 = pz;

    // ---- phase 1: z2[i] = b2[i] + sum_j sin(30*z1_j) * W2[j][i] ----
    float z2[HH];
    #pragma unroll
    for (int i = 0; i < HH; i += 4) {
        const float4 b = *(const float4*)(&sb2[i]);
        z2[i] = b.x; z2[i + 1] = b.y; z2[i + 2] = b.z; z2[i + 3] = b.w;
    }

    for (int j = 0; j < HH; ++j) {
        const float4 wa = *(const float4*)(&sW1[j * 8]);
        const float2 wb = *(const float2*)(&sW1[j * 8 + 4]);
        float z = wb.y;
        z = fmaf(x0, wa.x, z);
        z = fmaf(x1, wa.y, z);
        z = fmaf(x2, wa.z, z);
        z = fmaf(x3, wa.w, z);
        z = fmaf(x4, wb.x, z);
        const float h = __sinf(30.f * z);
        const float4* __restrict__ row = (const float4*)(&sW2[j * HH]);
        #pragma unroll
        for (int i = 0; i < HH; i += 4) {
            const float4 w = row[i >> 2];
            z2[i]     = fmaf(h, w.x, z2[i]);
            z2[i + 1] = fmaf(h, w.y, z2[i + 1]);
            z2[i + 2] = fmaf(h, w.z, z2[i + 2]);
            z2[i + 3] = fmaf(h, w.w, z2[i + 3]);
        }
    }

    // ---- phase 2: head fwd + transform z2 in place into t_i = W3_i*cos(z2_i) ----
    float sdf = b3v;
    #pragma unroll
    for (int i = 0; i < HH; i += 4) {
        const float4 w3 = *(const float4*)(&sW3[i]);
        const float s0 = __sinf(z2[i]),     c0 = __cosf(z2[i]);
        const float s1 = __sinf(z2[i + 1]), c1 = __cosf(z2[i + 1]);
        const float s2 = __sinf(z2[i + 2]), c2 = __cosf(z2[i + 2]);
        const float s3 = __sinf(z2[i + 3]), c3 = __cosf(z2[i + 3]);
        sdf = fmaf(s0, w3.x, sdf);
        sdf = fmaf(s1, w3.y, sdf);
        sdf = fmaf(s2, w3.z, sdf);
        sdf = fmaf(s3, w3.w, sdf);
        z2[i]     = w3.x * c0;
        z2[i + 1] = w3.y * c1;
        z2[i + 2] = w3.z * c2;
        z2[i + 3] = w3.w * c3;
    }

    // ---- phase 3: u_j = sum_i t_i*W2[j][i]; fold into dx via recomputed z1_j ----
    float d0 = 0.f, d1 = 0.f, d2 = 0.f, d3 = 0.f, d4 = 0.f;
    for (int j = 0; j < HH; ++j) {
        const float4* __restrict__ row = (const float4*)(&sW2[j * HH]);
        float a0 = 0.f, a1 = 0.f, a2 = 0.f, a3 = 0.f;
        #pragma unroll
        for (int i = 0; i < HH; i += 4) {
            const float4 w = row[i >> 2];
            a0 = fmaf(z2[i],     w.x, a0);
            a1 = fmaf(z2[i + 1], w.y, a1);
            a2 = fmaf(z2[i + 2], w.z, a2);
            a3 = fmaf(z2[i + 3], w.w, a3);
        }
        const float u = (a0 + a1) + (a2 + a3);
        const float4 wa = *(const float4*)(&sW1[j * 8]);
        const float2 wb = *(const float2*)(&sW1[j * 8 + 4]);
        float z = wb.y;
        z = fmaf(x0, wa.x, z);
        z = fmaf(x1, wa.y, z);
        z = fmaf(x2, wa.z, z);
        z = fmaf(x3, wa.w, z);
        z = fmaf(x4, wb.x, z);
        const float sj = u * 30.f * __cosf(30.f * z);
        d0 = fmaf(sj, wa.x, d0);
        d1 = fmaf(sj, wa.y, d1);
        d2 = fmaf(sj, wa.z, d2);
        d3 = fmaf(sj, wa.w, d3);
        d4 = fmaf(sj, wb.x, d4);
    }

    // ---- trilerp backward ----
    const float de0 = d0, de1 = d1;
    float gx, gy, gz;
    {
        const float2 r000 = g2[cbase];
        const float2 r001 = g2[cbase + 1];
        const float2 r010 = g2[cbase + RR];
        const float2 r011 = g2[cbase + RR + 1];
        const float2 r100 = g2[cbase + RR * RR];
        const float2 r101 = g2[cbase + RR * RR + 1];
        const float2 r110 = g2[cbase + RR * RR + RR];
        const float2 r111 = g2[cbase + RR * RR + RR + 1];
        const float q000 = r000.x * de0 + r000.y * de1;
        const float q001 = r001.x * de0 + r001.y * de1;
        const float q010 = r010.x * de0 + r010.y * de1;
        const float q011 = r011.x * de0 + r011.y * de1;
        const float q100 = r100.x * de0 + r100.y * de1;
        const float q101 = r101.x * de0 + r101.y * de1;
        const float q110 = r110.x * de0 + r110.y * de1;
        const float q111 = r111.x * de0 + r111.y * de1;
        gx = 7.5f * (wy0 * wz0 * (q100 - q000) + wy0 * wz1 * (q101 - q001)
                   + wy1 * wz0 * (q110 - q010) + wy1 * wz1 * (q111 - q011));
        gy = 7.5f * (wx0 * wz0 * (q010 - q000) + wx0 * wz1 * (q011 - q001)
                   + wx1 * wz0 * (q110 - q100) + wx1 * wz1 * (q111 - q101));
        gz = 7.5f * (wx0 * wy0 * (q001 - q000) + wx0 * wy1 * (q011 - q010)
                   + wx1 * wy0 * (q101 - q100) + wx1 * wy1 * (q111 - q110));
    }

    const bool m = (px >= -1.f) && (px <= 1.f) && (py >= -1.f) && (py <= 1.f)
                && (pz >= -1.f) && (pz <= 1.f);

    // ---- outputs: sdf (N), grad (N,3), mask (N) ----
    out[p] = sdf;
    out[N + 3 * p + 0] = d2 + gx;
    out[N + 3 * p + 1] = d3 + gy;
    out[N + 3 * p + 2] = d4 + gz;
    out[4 * N + p] = m ? 1.f : 0.f;
}

extern "C" void kernel_launch(void* const* d_in, const int* in_sizes, int n_in,
                              void* d_out, int out_size, void* d_ws, size_t ws_size,
                              hipStream_t stream) {
    const float* pos  = (const float*)d_in[0];
    const float* grid = (const float*)d_in[1];
    const float* W1   = (const float*)d_in[2];
    const float* b1   = (const float*)d_in[3];
    const float* W2   = (const float*)d_in[4];
    const float* b2   = (const float*)d_in[5];
    const float* W3   = (const float*)d_in[6];
    const float* b3   = (const float*)d_in[7];
    float* out = (float*)d_out;
    const int N = in_sizes[0] / 3;
    const int blocks = (N + 255) / 256;
    hipLaunchKernelGGL(siren_fused, dim3(blocks), dim3(256), 0, stream,
                       pos, grid, W1, b1, W2, b2, W3, b3, out, N);
}

// Round 3
// 1724.425 us; speedup vs baseline: 3.4380x; 1.2574x over previous
//
#include <hip/hip_runtime.h>
#include <math.h>

#define HH 128
#define RR 16

__global__ __launch_bounds__(256, 2)
void siren_fused(const float* __restrict__ pos,
                 const float* __restrict__ grid,
                 const float* __restrict__ W1, const float* __restrict__ b1,
                 const float* __restrict__ W2, const float* __restrict__ b2,
                 const float* __restrict__ W3, const float* __restrict__ b3,
                 float* __restrict__ out, int N)
{
    __shared__ float sW2[HH * HH];  // row-major: sW2[j*HH + i] = W2[j][i]
    __shared__ float sW1[HH * 8];   // sW1[j*8+k]: k<5 -> W1[k][j], k==5 -> b1[j]
    __shared__ float sb2[HH];
    __shared__ float sW3[HH];

    const int tid = threadIdx.x;

    // ---- cooperative staging (coalesced, no transpose, no conflicts) ----
    {
        const float4* __restrict__ W2v = (const float4*)W2;
        float4* sW2v = (float4*)sW2;
        #pragma unroll
        for (int it = 0; it < (HH * HH / 4) / 256; ++it)
            sW2v[it * 256 + tid] = W2v[it * 256 + tid];
    }
    if (tid < HH) {
        sb2[tid] = b2[tid];
        sW3[tid] = W3[tid];
        #pragma unroll
        for (int k = 0; k < 5; ++k) sW1[tid * 8 + k] = W1[k * HH + tid];
        sW1[tid * 8 + 5] = b1[tid];
        sW1[tid * 8 + 6] = 0.f;
        sW1[tid * 8 + 7] = 0.f;
    }
    const float b3v = b3[0];
    __syncthreads();

    const int p = blockIdx.x * 256 + tid;
    if (p >= N) return;

    const float px = pos[p * 3 + 0];
    const float py = pos[p * 3 + 1];
    const float pz = pos[p * 3 + 2];

    // ---- trilerp forward ----
    const float ux = (px + 1.f) * 7.5f;
    const float uy = (py + 1.f) * 7.5f;
    const float uz = (pz + 1.f) * 7.5f;
    int ix = (int)floorf(ux); ix = ix < 0 ? 0 : (ix > RR - 2 ? RR - 2 : ix);
    int iy = (int)floorf(uy); iy = iy < 0 ? 0 : (iy > RR - 2 ? RR - 2 : iy);
    int iz = (int)floorf(uz); iz = iz < 0 ? 0 : (iz > RR - 2 ? RR - 2 : iz);
    const float fx = ux - (float)ix;
    const float fy = uy - (float)iy;
    const float fz = uz - (float)iz;

    const float2* __restrict__ g2 = (const float2*)grid;
    const int cbase = (ix * RR + iy) * RR + iz;

    float e0, e1;
    float wx0, wx1, wy0, wy1, wz0, wz1;
    {
        const float2 c000 = g2[cbase];
        const float2 c001 = g2[cbase + 1];
        const float2 c010 = g2[cbase + RR];
        const float2 c011 = g2[cbase + RR + 1];
        const float2 c100 = g2[cbase + RR * RR];
        const float2 c101 = g2[cbase + RR * RR + 1];
        const float2 c110 = g2[cbase + RR * RR + RR];
        const float2 c111 = g2[cbase + RR * RR + RR + 1];
        wx0 = 1.f - fx; wx1 = fx;
        wy0 = 1.f - fy; wy1 = fy;
        wz0 = 1.f - fz; wz1 = fz;
        const float w000 = wx0 * wy0 * wz0, w001 = wx0 * wy0 * wz1;
        const float w010 = wx0 * wy1 * wz0, w011 = wx0 * wy1 * wz1;
        const float w100 = wx1 * wy0 * wz0, w101 = wx1 * wy0 * wz1;
        const float w110 = wx1 * wy1 * wz0, w111 = wx1 * wy1 * wz1;
        e0 = w000 * c000.x + w001 * c001.x + w010 * c010.x + w011 * c011.x
           + w100 * c100.x + w101 * c101.x + w110 * c110.x + w111 * c111.x;
        e1 = w000 * c000.y + w001 * c001.y + w010 * c010.y + w011 * c011.y
           + w100 * c100.y + w101 * c101.y + w110 * c110.y + w111 * c111.y;
    }

    const float x0 = e0, x1 = e1, x2 = px, x3 = py, x4 = pz;

    float d0 = 0.f, d1 = 0.f, d2 = 0.f, d3 = 0.f, d4 = 0.f;
    float sdf = b3v;

    // ==== process hidden-i dimension in two halves of 64 to keep the live
    //      per-point state at 64 floats (+temps) -> zero scratch spill ====
    #pragma unroll 1
    for (int half = 0; half < 2; ++half) {
        const int base = half << 6;

        // ---- phase 1: z2[i] = b2[base+i] + sum_j sin(30*z1_j)*W2[j][base+i] ----
        float z2[64];
        #pragma unroll
        for (int i = 0; i < 64; i += 4) {
            const float4 b = *(const float4*)(&sb2[base + i]);
            z2[i] = b.x; z2[i + 1] = b.y; z2[i + 2] = b.z; z2[i + 3] = b.w;
        }

        #pragma unroll 1
        for (int j = 0; j < HH; ++j) {
            const float4 wa = *(const float4*)(&sW1[j * 8]);
            const float2 wb = *(const float2*)(&sW1[j * 8 + 4]);
            float z = wb.y;
            z = fmaf(x0, wa.x, z);
            z = fmaf(x1, wa.y, z);
            z = fmaf(x2, wa.z, z);
            z = fmaf(x3, wa.w, z);
            z = fmaf(x4, wb.x, z);
            const float h = __sinf(30.f * z);
            const float4* __restrict__ row = (const float4*)(&sW2[j * HH + base]);
            #pragma unroll
            for (int i = 0; i < 64; i += 4) {
                const float4 w = row[i >> 2];
                z2[i]     = fmaf(h, w.x, z2[i]);
                z2[i + 1] = fmaf(h, w.y, z2[i + 1]);
                z2[i + 2] = fmaf(h, w.z, z2[i + 2]);
                z2[i + 3] = fmaf(h, w.w, z2[i + 3]);
            }
        }

        // ---- phase 2: sdf += sin(z2)*W3; z2 -> t = W3*cos(z2) in place ----
        #pragma unroll
        for (int i = 0; i < 64; i += 4) {
            const float4 w3 = *(const float4*)(&sW3[base + i]);
            const float s0 = __sinf(z2[i]),     c0 = __cosf(z2[i]);
            const float s1 = __sinf(z2[i + 1]), c1 = __cosf(z2[i + 1]);
            const float s2 = __sinf(z2[i + 2]), c2 = __cosf(z2[i + 2]);
            const float s3 = __sinf(z2[i + 3]), c3 = __cosf(z2[i + 3]);
            sdf = fmaf(s0, w3.x, sdf);
            sdf = fmaf(s1, w3.y, sdf);
            sdf = fmaf(s2, w3.z, sdf);
            sdf = fmaf(s3, w3.w, sdf);
            z2[i]     = w3.x * c0;
            z2[i + 1] = w3.y * c1;
            z2[i + 2] = w3.z * c2;
            z2[i + 3] = w3.w * c3;
        }

        // ---- phase 3: partial u_j = sum_{i in half} t_i*W2[j][base+i];
        //      fold into dx via recomputed z1_j (linear in i-partition) ----
        #pragma unroll 1
        for (int j = 0; j < HH; ++j) {
            const float4* __restrict__ row = (const float4*)(&sW2[j * HH + base]);
            float a0 = 0.f, a1 = 0.f, a2 = 0.f, a3 = 0.f;
            #pragma unroll
            for (int i = 0; i < 64; i += 4) {
                const float4 w = row[i >> 2];
                a0 = fmaf(z2[i],     w.x, a0);
                a1 = fmaf(z2[i + 1], w.y, a1);
                a2 = fmaf(z2[i + 2], w.z, a2);
                a3 = fmaf(z2[i + 3], w.w, a3);
            }
            const float u = (a0 + a1) + (a2 + a3);
            const float4 wa = *(const float4*)(&sW1[j * 8]);
            const float2 wb = *(const float2*)(&sW1[j * 8 + 4]);
            float z = wb.y;
            z = fmaf(x0, wa.x, z);
            z = fmaf(x1, wa.y, z);
            z = fmaf(x2, wa.z, z);
            z = fmaf(x3, wa.w, z);
            z = fmaf(x4, wb.x, z);
            const float sj = u * 30.f * __cosf(30.f * z);
            d0 = fmaf(sj, wa.x, d0);
            d1 = fmaf(sj, wa.y, d1);
            d2 = fmaf(sj, wa.z, d2);
            d3 = fmaf(sj, wa.w, d3);
            d4 = fmaf(sj, wb.x, d4);
        }
    }

    // ---- trilerp backward ----
    const float de0 = d0, de1 = d1;
    float gx, gy, gz;
    {
        const float2 r000 = g2[cbase];
        const float2 r001 = g2[cbase + 1];
        const float2 r010 = g2[cbase + RR];
        const float2 r011 = g2[cbase + RR + 1];
        const float2 r100 = g2[cbase + RR * RR];
        const float2 r101 = g2[cbase + RR * RR + 1];
        const float2 r110 = g2[cbase + RR * RR + RR];
        const float2 r111 = g2[cbase + RR * RR + RR + 1];
        const float q000 = r000.x * de0 + r000.y * de1;
        const float q001 = r001.x * de0 + r001.y * de1;
        const float q010 = r010.x * de0 + r010.y * de1;
        const float q011 = r011.x * de0 + r011.y * de1;
        const float q100 = r100.x * de0 + r100.y * de1;
        const float q101 = r101.x * de0 + r101.y * de1;
        const float q110 = r110.x * de0 + r110.y * de1;
        const float q111 = r111.x * de0 + r111.y * de1;
        gx = 7.5f * (wy0 * wz0 * (q100 - q000) + wy0 * wz1 * (q101 - q001)
                   + wy1 * wz0 * (q110 - q010) + wy1 * wz1 * (q111 - q011));
        gy = 7.5f * (wx0 * wz0 * (q010 - q000) + wx0 * wz1 * (q011 - q001)
                   + wx1 * wz0 * (q110 - q100) + wx1 * wz1 * (q111 - q101));
        gz = 7.5f * (wx0 * wy0 * (q001 - q000) + wx0 * wy1 * (q011 - q010)
                   + wx1 * wy0 * (q101 - q100) + wx1 * wy1 * (q111 - q110));
    }

    const bool m = (px >= -1.f) && (px <= 1.f) && (py >= -1.f) && (py <= 1.f)
                && (pz >= -1.f) && (pz <= 1.f);

    // ---- outputs: sdf (N), grad (N,3), mask (N) ----
    out[p] = sdf;
    out[N + 3 * p + 0] = d2 + gx;
    out[N + 3 * p + 1] = d3 + gy;
    out[N + 3 * p + 2] = d4 + gz;
    out[4 * N + p] = m ? 1.f : 0.f;
}

extern "C" void kernel_launch(void* const* d_in, const int* in_sizes, int n_in,
                              void* d_out, int out_size, void* d_ws, size_t ws_size,
                              hipStream_t stream) {
    const float* pos  = (const float*)d_in[0];
    const float* grid = (const float*)d_in[1];
    const float* W1   = (const float*)d_in[2];
    const float* b1   = (const float*)d_in[3];
    const float* W2   = (const float*)d_in[4];
    const float* b2   = (const float*)d_in[5];
    const float* W3   = (const float*)d_in[6];
    const float* b3   = (const float*)d_in[7];
    float* out = (float*)d_out;
    const int N = in_sizes[0] / 3;
    const int blocks = (N + 255) / 256;
    hipLaunchKernelGGL(siren_fused, dim3(blocks), dim3(256), 0, stream,
                       pos, grid, W1, b1, W2, b2, W3, b3, out, N);
}

// Round 4
// 445.890 us; speedup vs baseline: 13.2959x; 3.8674x over previous
//
#include <hip/hip_runtime.h>
#include <math.h>

#define RR 16

typedef __attribute__((ext_vector_type(8))) short bf16x8;
typedef __attribute__((ext_vector_type(4))) short short4v;
typedef __attribute__((ext_vector_type(4))) float f32x4;

#define MFMA16(a, b, c) __builtin_amdgcn_mfma_f32_16x16x32_bf16((a), (b), (c), 0, 0, 0)

static __device__ __forceinline__ unsigned short f2bf(float f) {
    union { float f; unsigned u; } v; v.f = f;
    unsigned r = v.u + 0x7fffu + ((v.u >> 16) & 1u);
    return (unsigned short)(r >> 16);
}
static __device__ __forceinline__ float bf2f(unsigned short h) {
    union { float f; unsigned u; } v; v.u = ((unsigned)h) << 16; return v.f;
}

// swizzled addressing: logical (row, col) of a [R][256B-row] short array,
// byte = row*256 + col*2, XOR'd with (row&7)<<4  (write and read use same map)
static __device__ __forceinline__ short* swz256(short* base, int row, int col) {
    int b = (row << 8) + (col << 1);
    return (short*)((char*)base + (b ^ ((row & 7) << 4)));
}
static __device__ __forceinline__ const short* cswz256(const short* base, int row, int col) {
    int b = (row << 8) + (col << 1);
    return (const short*)((const char*)base + (b ^ ((row & 7) << 4)));
}
// 64-byte rows (W1T [128][32])
static __device__ __forceinline__ short* swz64(short* base, int row, int col) {
    int b = (row << 6) + (col << 1);
    return (short*)((char*)base + (b ^ ((row & 3) << 4)));
}
static __device__ __forceinline__ const short* cswz64(const short* base, int row, int col) {
    int b = (row << 6) + (col << 1);
    return (const short*)((const char*)base + (b ^ ((row & 3) << 4)));
}

__global__ __launch_bounds__(256, 1)
void siren_mfma(const float* __restrict__ pos, const float* __restrict__ grid,
                const float* __restrict__ W1, const float* __restrict__ b1,
                const float* __restrict__ W2, const float* __restrict__ b2,
                const float* __restrict__ W3, const float* __restrict__ b3,
                float* __restrict__ out, int N)
{
    // ---- LDS (160,768 B total) ----
    __shared__ short sW2T_hi[128 * 128];  // [i][j] = W2[j][i]
    __shared__ short sW2T_lo[128 * 128];
    __shared__ short sW2N_hi[128 * 128];  // [j][i] = W2[j][i]
    __shared__ short sW1T_hi[128 * 32];   // [j][k]: k<5 = W1[k][j], k==5 = b1[j], else 0
    __shared__ short sW1T_lo[128 * 32];
    __shared__ short sW1B_hi[16 * 128];   // [k][j]: k<5 = W1[k][j], else 0
    __shared__ short sW1B_lo[16 * 128];
    __shared__ float sb2[128];
    __shared__ float sW3[128];
    __shared__ short sHTS_hi[4][16 * 128]; // per-wave [p][feat] (h -> t -> s, reused)
    __shared__ short sHTS_lo[4][16 * 128];
    __shared__ short sX_hi[4][16 * 8];     // per-wave [p][k] (x0,x1,px,py,pz,1,0,0)
    __shared__ short sX_lo[4][16 * 8];
    __shared__ float sDX[4][16 * 8];       // per-wave dx redistribution

    const int tid = threadIdx.x;

    // ================= weight staging (once per block) =================
    {   // W2T hi+lo : transpose, coalesced reads per e
        const int i = tid & 127;
        const int j0 = (tid >> 7) * 64;
        for (int u = 0; u < 64; u += 4) {
            short4v h4, l4;
            #pragma unroll
            for (int e = 0; e < 4; ++e) {
                const float w = W2[(j0 + u + e) * 128 + i];
                const unsigned short hs = f2bf(w);
                h4[e] = (short)hs;
                l4[e] = (short)f2bf(w - bf2f(hs));
            }
            *(short4v*)swz256(sW2T_hi, i, j0 + u) = h4;
            *(short4v*)swz256(sW2T_lo, i, j0 + u) = l4;
        }
    }
    {   // W2N hi : native orientation
        const float4* W2v = (const float4*)W2;
        for (int k = 0; k < 16; ++k) {
            const int idx = k * 256 + tid;           // float4 index
            const float4 w = W2v[idx];
            const int j = idx >> 5;
            const int i0 = (idx << 2) & 127;
            short4v h4;
            h4[0] = (short)f2bf(w.x); h4[1] = (short)f2bf(w.y);
            h4[2] = (short)f2bf(w.z); h4[3] = (short)f2bf(w.w);
            *(short4v*)swz256(sW2N_hi, j, i0) = h4;
        }
    }
    if (tid < 128) {
        const int j = tid;
        float v[6];
        #pragma unroll
        for (int k = 0; k < 5; ++k) v[k] = W1[k * 128 + j];
        v[5] = b1[j];
        short hrow[32], lrow[32];
        #pragma unroll
        for (int k = 0; k < 32; ++k) { hrow[k] = 0; lrow[k] = 0; }
        #pragma unroll
        for (int k = 0; k < 6; ++k) {
            const unsigned short hs = f2bf(v[k]);
            hrow[k] = (short)hs;
            lrow[k] = (short)f2bf(v[k] - bf2f(hs));
        }
        #pragma unroll
        for (int kb = 0; kb < 32; kb += 8) {
            *(bf16x8*)swz64(sW1T_hi, j, kb) = *(bf16x8*)&hrow[kb];
            *(bf16x8*)swz64(sW1T_lo, j, kb) = *(bf16x8*)&lrow[kb];
        }
        #pragma unroll
        for (int k = 0; k < 16; ++k) {
            const float wv = (k < 5) ? W1[k * 128 + j] : 0.f;
            const unsigned short hs = f2bf(wv);
            *swz256(sW1B_hi, k, j) = (short)hs;
            *swz256(sW1B_lo, k, j) = (short)f2bf(wv - bf2f(hs));
        }
        sb2[j] = b2[j];
        sW3[j] = W3[j];
    }
    const float b3v = b3[0];
    __syncthreads();

    // ================= main loop: 16 point-tiles of 16 per wave =================
    const int lane = tid & 63;
    const int wv = tid >> 6;
    const int g = lane >> 4;    // k-group / C-row group
    const int m = lane & 15;    // point-local index (C column)

    short* hts_h = sHTS_hi[wv];
    short* hts_l = sHTS_lo[wv];
    const float2* __restrict__ g2 = (const float2*)grid;

    for (int pt = 0; pt < 16; ++pt) {
        const int p = blockIdx.x * 1024 + wv * 256 + pt * 16 + m;
        const int pc = (p < N) ? p : (N - 1);

        const float px = pos[3 * pc + 0];
        const float py = pos[3 * pc + 1];
        const float pz = pos[3 * pc + 2];

        // ---- trilerp forward (all lanes, redundant across g) ----
        const float ux = (px + 1.f) * 7.5f;
        const float uy = (py + 1.f) * 7.5f;
        const float uz = (pz + 1.f) * 7.5f;
        int ix = (int)floorf(ux); ix = ix < 0 ? 0 : (ix > RR - 2 ? RR - 2 : ix);
        int iy = (int)floorf(uy); iy = iy < 0 ? 0 : (iy > RR - 2 ? RR - 2 : iy);
        int iz = (int)floorf(uz); iz = iz < 0 ? 0 : (iz > RR - 2 ? RR - 2 : iz);
        const float fx = ux - (float)ix;
        const float fy = uy - (float)iy;
        const float fz = uz - (float)iz;
        const int cbase = (ix * RR + iy) * RR + iz;
        const float wx0 = 1.f - fx, wx1 = fx;
        const float wy0 = 1.f - fy, wy1 = fy;
        const float wz0 = 1.f - fz, wz1 = fz;
        float e0, e1;
        {
            const float2 c000 = g2[cbase];
            const float2 c001 = g2[cbase + 1];
            const float2 c010 = g2[cbase + RR];
            const float2 c011 = g2[cbase + RR + 1];
            const float2 c100 = g2[cbase + RR * RR];
            const float2 c101 = g2[cbase + RR * RR + 1];
            const float2 c110 = g2[cbase + RR * RR + RR];
            const float2 c111 = g2[cbase + RR * RR + RR + 1];
            const float w000 = wx0 * wy0 * wz0, w001 = wx0 * wy0 * wz1;
            const float w010 = wx0 * wy1 * wz0, w011 = wx0 * wy1 * wz1;
            const float w100 = wx1 * wy0 * wz0, w101 = wx1 * wy0 * wz1;
            const float w110 = wx1 * wy1 * wz0, w111 = wx1 * wy1 * wz1;
            e0 = w000 * c000.x + w001 * c001.x + w010 * c010.x + w011 * c011.x
               + w100 * c100.x + w101 * c101.x + w110 * c110.x + w111 * c111.x;
            e1 = w000 * c000.y + w001 * c001.y + w010 * c010.y + w011 * c011.y
               + w100 * c100.y + w101 * c101.y + w110 * c110.y + w111 * c111.y;
        }

        // ---- stage x row (lanes 0..15 only) ----
        if (lane < 16) {
            bf16x8 xh, xl;
            const float xv0 = e0, xv1 = e1, xv2 = px, xv3 = py, xv4 = pz, xv5 = 1.f;
            unsigned short hs;
            hs = f2bf(xv0); xh[0] = (short)hs; xl[0] = (short)f2bf(xv0 - bf2f(hs));
            hs = f2bf(xv1); xh[1] = (short)hs; xl[1] = (short)f2bf(xv1 - bf2f(hs));
            hs = f2bf(xv2); xh[2] = (short)hs; xl[2] = (short)f2bf(xv2 - bf2f(hs));
            hs = f2bf(xv3); xh[3] = (short)hs; xl[3] = (short)f2bf(xv3 - bf2f(hs));
            hs = f2bf(xv4); xh[4] = (short)hs; xl[4] = (short)f2bf(xv4 - bf2f(hs));
            hs = f2bf(xv5); xh[5] = (short)hs; xl[5] = (short)f2bf(xv5 - bf2f(hs));
            xh[6] = 0; xh[7] = 0; xl[6] = 0; xl[7] = 0;
            *(bf16x8*)&sX_hi[wv][m * 8] = xh;
            *(bf16x8*)&sX_lo[wv][m * 8] = xl;
        }

        // ---- G0t: z1^T[j][p] = W1T (hi/lo) x x (hi/lo), K=32 single step ----
        // B-read is g-independent (16B row of x); A has zeros for k>=6 so the
        // replicated B values contract to the exact 6-term dot product.
        const bf16x8 xbh = *(const bf16x8*)&sX_hi[wv][m * 8];
        const bf16x8 xbl = *(const bf16x8*)&sX_lo[wv][m * 8];
        f32x4 c0[8];
        #pragma unroll
        for (int jt = 0; jt < 8; ++jt) {
            const bf16x8 ah = *(const bf16x8*)cswz64(sW1T_hi, jt * 16 + m, 8 * g);
            const bf16x8 al = *(const bf16x8*)cswz64(sW1T_lo, jt * 16 + m, 8 * g);
            f32x4 c = {0.f, 0.f, 0.f, 0.f};
            c = MFMA16(ah, xbh, c);
            c = MFMA16(ah, xbl, c);
            c = MFMA16(al, xbh, c);
            c0[jt] = c;
        }

        // ---- h = sin(30*z1), split, write to hts[p][j] ----
        #pragma unroll
        for (int jt = 0; jt < 8; ++jt) {
            short4v h4, l4;
            #pragma unroll
            for (int r = 0; r < 4; ++r) {
                const float h = __sinf(30.f * c0[jt][r]);
                const unsigned short hs = f2bf(h);
                h4[r] = (short)hs;
                l4[r] = (short)f2bf(h - bf2f(hs));
            }
            *(short4v*)swz256(hts_h, m, jt * 16 + 4 * g) = h4;
            *(short4v*)swz256(hts_l, m, jt * 16 + 4 * g) = l4;
        }

        // ---- G1t: z2^T[i][p] = W2T(hi/lo) x h(hi/lo), 3-term ----
        f32x4 c1[8];
        #pragma unroll
        for (int it = 0; it < 8; ++it) c1[it] = (f32x4){0.f, 0.f, 0.f, 0.f};
        #pragma unroll
        for (int ks = 0; ks < 4; ++ks) {
            const bf16x8 bh = *(const bf16x8*)cswz256(hts_h, m, ks * 32 + 8 * g);
            const bf16x8 bl = *(const bf16x8*)cswz256(hts_l, m, ks * 32 + 8 * g);
            #pragma unroll
            for (int it = 0; it < 8; ++it) {
                const bf16x8 ah = *(const bf16x8*)cswz256(sW2T_hi, it * 16 + m, ks * 32 + 8 * g);
                const bf16x8 al = *(const bf16x8*)cswz256(sW2T_lo, it * 16 + m, ks * 32 + 8 * g);
                c1[it] = MFMA16(ah, bh, c1[it]);
                c1[it] = MFMA16(ah, bl, c1[it]);
                c1[it] = MFMA16(al, bh, c1[it]);
            }
        }

        // ---- phase 2: sdf partial + t = W3*cos(z2), write t over h ----
        float sdfp = 0.f;
        #pragma unroll
        for (int it = 0; it < 8; ++it) {
            const f32x4 b2v = *(const f32x4*)&sb2[it * 16 + 4 * g];
            const f32x4 w3v = *(const f32x4*)&sW3[it * 16 + 4 * g];
            short4v h4, l4;
            #pragma unroll
            for (int r = 0; r < 4; ++r) {
                const float z2 = c1[it][r] + b2v[r];
                const float s2 = __sinf(z2);
                const float cc = __cosf(z2);
                sdfp = fmaf(w3v[r], s2, sdfp);
                const float t = w3v[r] * cc;
                const unsigned short hs = f2bf(t);
                h4[r] = (short)hs;
                l4[r] = (short)f2bf(t - bf2f(hs));
            }
            *(short4v*)swz256(hts_h, m, it * 16 + 4 * g) = h4;
            *(short4v*)swz256(hts_l, m, it * 16 + 4 * g) = l4;
        }
        sdfp += __shfl_xor(sdfp, 16);
        sdfp += __shfl_xor(sdfp, 32);
        const float sdf = b3v + sdfp;

        // ---- G2t: u^T[j][p] = W2N(hi) x t(hi/lo), 2-term ----
        f32x4 c2[8];
        #pragma unroll
        for (int jt = 0; jt < 8; ++jt) c2[jt] = (f32x4){0.f, 0.f, 0.f, 0.f};
        #pragma unroll
        for (int ks = 0; ks < 4; ++ks) {
            const bf16x8 bh = *(const bf16x8*)cswz256(hts_h, m, ks * 32 + 8 * g);
            const bf16x8 bl = *(const bf16x8*)cswz256(hts_l, m, ks * 32 + 8 * g);
            #pragma unroll
            for (int jt = 0; jt < 8; ++jt) {
                const bf16x8 a = *(const bf16x8*)cswz256(sW2N_hi, jt * 16 + m, ks * 32 + 8 * g);
                c2[jt] = MFMA16(a, bh, c2[jt]);
                c2[jt] = MFMA16(a, bl, c2[jt]);
            }
        }

        // ---- phase 3: s_j = u_j * 30 * cos(30*z1_j), write s over t ----
        #pragma unroll
        for (int jt = 0; jt < 8; ++jt) {
            short4v h4, l4;
            #pragma unroll
            for (int r = 0; r < 4; ++r) {
                const float sj = c2[jt][r] * 30.f * __cosf(30.f * c0[jt][r]);
                const unsigned short hs = f2bf(sj);
                h4[r] = (short)hs;
                l4[r] = (short)f2bf(sj - bf2f(hs));
            }
            *(short4v*)swz256(hts_h, m, jt * 16 + 4 * g) = h4;
            *(short4v*)swz256(hts_l, m, jt * 16 + 4 * g) = l4;
        }

        // ---- G3t: dx[k][p] = W1B(hi/lo) x s(hi/lo), 3-term ----
        f32x4 c3 = {0.f, 0.f, 0.f, 0.f};
        #pragma unroll
        for (int ks = 0; ks < 4; ++ks) {
            const bf16x8 bh = *(const bf16x8*)cswz256(hts_h, m, ks * 32 + 8 * g);
            const bf16x8 bl = *(const bf16x8*)cswz256(hts_l, m, ks * 32 + 8 * g);
            const bf16x8 ah = *(const bf16x8*)cswz256(sW1B_hi, m, ks * 32 + 8 * g);
            const bf16x8 al = *(const bf16x8*)cswz256(sW1B_lo, m, ks * 32 + 8 * g);
            c3 = MFMA16(ah, bh, c3);
            c3 = MFMA16(ah, bl, c3);
            c3 = MFMA16(al, bh, c3);
        }
        if (g < 2) *(f32x4*)&sDX[wv][m * 8 + 4 * g] = c3;

        // ---- outputs (lanes 0..15) ----
        if (lane < 16 && p < N) {
            const f32x4 dxa = *(const f32x4*)&sDX[wv][m * 8];
            const float d4 = sDX[wv][m * 8 + 4];
            const float de0 = dxa[0], de1 = dxa[1];
            float gx, gy, gz;
            {
                const float2 r000 = g2[cbase];
                const float2 r001 = g2[cbase + 1];
                const float2 r010 = g2[cbase + RR];
                const float2 r011 = g2[cbase + RR + 1];
                const float2 r100 = g2[cbase + RR * RR];
                const float2 r101 = g2[cbase + RR * RR + 1];
                const float2 r110 = g2[cbase + RR * RR + RR];
                const float2 r111 = g2[cbase + RR * RR + RR + 1];
                const float q000 = r000.x * de0 + r000.y * de1;
                const float q001 = r001.x * de0 + r001.y * de1;
                const float q010 = r010.x * de0 + r010.y * de1;
                const float q011 = r011.x * de0 + r011.y * de1;
                const float q100 = r100.x * de0 + r100.y * de1;
                const float q101 = r101.x * de0 + r101.y * de1;
                const float q110 = r110.x * de0 + r110.y * de1;
                const float q111 = r111.x * de0 + r111.y * de1;
                gx = 7.5f * (wy0 * wz0 * (q100 - q000) + wy0 * wz1 * (q101 - q001)
                           + wy1 * wz0 * (q110 - q010) + wy1 * wz1 * (q111 - q011));
                gy = 7.5f * (wx0 * wz0 * (q010 - q000) + wx0 * wz1 * (q011 - q001)
                           + wx1 * wz0 * (q110 - q100) + wx1 * wz1 * (q111 - q101));
                gz = 7.5f * (wx0 * wy0 * (q001 - q000) + wx0 * wy1 * (q011 - q010)
                           + wx1 * wy0 * (q101 - q100) + wx1 * wy1 * (q111 - q110));
            }
            const bool msk = (px >= -1.f) && (px <= 1.f) && (py >= -1.f) && (py <= 1.f)
                          && (pz >= -1.f) && (pz <= 1.f);
            out[p] = sdf;
            out[N + 3 * p + 0] = dxa[2] + gx;
            out[N + 3 * p + 1] = dxa[3] + gy;
            out[N + 3 * p + 2] = d4 + gz;
            out[4 * N + p] = msk ? 1.f : 0.f;
        }
    }
}

extern "C" void kernel_launch(void* const* d_in, const int* in_sizes, int n_in,
                              void* d_out, int out_size, void* d_ws, size_t ws_size,
                              hipStream_t stream) {
    const float* pos  = (const float*)d_in[0];
    const float* grid = (const float*)d_in[1];
    const float* W1   = (const float*)d_in[2];
    const float* b1   = (const float*)d_in[3];
    const float* W2   = (const float*)d_in[4];
    const float* b2   = (const float*)d_in[5];
    const float* W3   = (const float*)d_in[6];
    const float* b3   = (const float*)d_in[7];
    float* out = (float*)d_out;
    const int N = in_sizes[0] / 3;
    const int blocks = (N + 1023) / 1024;
    hipLaunchKernelGGL(siren_mfma, dim3(blocks), dim3(256), 0, stream,
                       pos, grid, W1, b1, W2, b2, W3, b3, out, N);
}

// Round 5
// 241.478 us; speedup vs baseline: 24.5509x; 1.8465x over previous
//
#include <hip/hip_runtime.h>
#include <math.h>

#define RR 16

typedef __attribute__((ext_vector_type(8))) short bf16x8;
typedef __attribute__((ext_vector_type(4))) short short4v;
typedef __attribute__((ext_vector_type(4))) float f32x4;

#define MFMA16(a, b, c) __builtin_amdgcn_mfma_f32_16x16x32_bf16((a), (b), (c), 0, 0, 0)

static __device__ __forceinline__ unsigned short f2bf(float f) {
    union { float f; unsigned u; } v; v.f = f;
    unsigned r = v.u + 0x7fffu + ((v.u >> 16) & 1u);
    return (unsigned short)(r >> 16);
}
static __device__ __forceinline__ float bf2f(unsigned short h) {
    union { float f; unsigned u; } v; v.u = ((unsigned)h) << 16; return v.f;
}

// All MFMA operands are stored lane-linear: fragment for (tile, ks) lives at
// short-index  tile*2048(or 512) + ks*512 + lane*8  -> ds_read_b128 at
// base + lane*16 bytes + compile-time offset. Conflict-free by construction.

__global__ __launch_bounds__(512, 2)
void siren_mfma(const float* __restrict__ pos, const float* __restrict__ grid,
                const float* __restrict__ W1, const float* __restrict__ b1,
                const float* __restrict__ W2, const float* __restrict__ b2,
                const float* __restrict__ W3, const float* __restrict__ b3,
                float* __restrict__ out, int N)
{
    // ---- LDS: 156,672 B ----
    __shared__ short sW2T[128 * 128];    // A of G1: (i=it*16+m, j=ks*32+8g+e), hi only
    __shared__ short sW2N[128 * 128];    // A of G2: (j=jt*16+m, i=ks*32+8g+e), hi only
    __shared__ short sW1T_h[128 * 32];   // A of G0: (j=jt*16+m, k=8g+e) k<5=W1,k==5=b1
    __shared__ short sW1T_l[128 * 32];
    __shared__ short sW1B_h[16 * 128];   // A of G3: (k=m, j=ks*32+8g+e), k<5=W1 else 0
    __shared__ short sW1B_l[16 * 128];
    __shared__ float sb2[128];
    __shared__ float sW3[128];
    __shared__ short sHTS_h[8][16 * 128]; // per-wave [point m][feature] h -> t -> s
    __shared__ short sHTS_l[8][16 * 128];

    const int tid = threadIdx.x;

    // ================= weight staging (once per block, 512 threads) =================
    {   // W2T: thread (i = tid&127, ks = tid>>7) covers j = ks*32 .. +31
        const int i = tid & 127, ks = tid >> 7;
        const int base = ((i >> 4) * 2048) + ks * 512 + (i & 15) * 8;
        #pragma unroll
        for (int g = 0; g < 4; ++g) {
            bf16x8 h8;
            #pragma unroll
            for (int e = 0; e < 8; ++e)
                h8[e] = (short)f2bf(W2[(ks * 32 + g * 8 + e) * 128 + i]);
            *(bf16x8*)&sW2T[base + g * 128] = h8;
        }
    }
    {   // W2N: thread (j = tid&127, ks = tid>>7) covers i = ks*32 .. +31 (contiguous)
        const int j = tid & 127, ks = tid >> 7;
        const int base = ((j >> 4) * 2048) + ks * 512 + (j & 15) * 8;
        const float4* __restrict__ w4 = (const float4*)&W2[j * 128 + ks * 32];
        #pragma unroll
        for (int g = 0; g < 4; ++g) {
            const float4 a = w4[g * 2];
            const float4 b = w4[g * 2 + 1];
            bf16x8 h8;
            h8[0] = (short)f2bf(a.x); h8[1] = (short)f2bf(a.y);
            h8[2] = (short)f2bf(a.z); h8[3] = (short)f2bf(a.w);
            h8[4] = (short)f2bf(b.x); h8[5] = (short)f2bf(b.y);
            h8[6] = (short)f2bf(b.z); h8[7] = (short)f2bf(b.w);
            *(bf16x8*)&sW2N[base + g * 128] = h8;
        }
    }
    if (tid < 128) {   // W1T hi/lo (+ zero padding of k>=6)
        const int j = tid;
        const int base = ((j >> 4) * 512) + (j & 15) * 8;
        bf16x8 h8, l8;
        #pragma unroll
        for (int e = 0; e < 8; ++e) {
            const float v = (e < 5) ? W1[e * 128 + j] : (e == 5 ? b1[j] : 0.f);
            const unsigned short hs = f2bf(v);
            h8[e] = (short)hs;
            l8[e] = (short)f2bf(v - bf2f(hs));
        }
        *(bf16x8*)&sW1T_h[base] = h8;
        *(bf16x8*)&sW1T_l[base] = l8;
        bf16x8 z8 = {0, 0, 0, 0, 0, 0, 0, 0};
        #pragma unroll
        for (int g = 1; g < 4; ++g) {
            *(bf16x8*)&sW1T_h[base + g * 128] = z8;
            *(bf16x8*)&sW1T_l[base + g * 128] = z8;
        }
        sb2[j] = b2[j];
        sW3[j] = W3[j];
    }
    if (tid < 256) {   // W1B hi/lo: group (k = tid&15, g = (tid>>4)&3, ks = tid>>6)
        const int k = tid & 15, gg = (tid >> 4) & 3, ks = tid >> 6;
        const int base = ks * 512 + gg * 128 + k * 8;
        bf16x8 h8, l8;
        #pragma unroll
        for (int e = 0; e < 8; ++e) {
            const int j = ks * 32 + gg * 8 + e;
            const float v = (k < 5) ? W1[k * 128 + j] : 0.f;
            const unsigned short hs = f2bf(v);
            h8[e] = (short)hs;
            l8[e] = (short)f2bf(v - bf2f(hs));
        }
        *(bf16x8*)&sW1B_h[base] = h8;
        *(bf16x8*)&sW1B_l[base] = l8;
    }
    const float b3v = b3[0];
    __syncthreads();

    // ================= main loop: 16 point-tiles of 16 per wave =================
    const int lane = tid & 63;
    const int wv = tid >> 6;
    const int g = lane >> 4;
    const int m = lane & 15;

    short* __restrict__ hh = sHTS_h[wv];
    short* __restrict__ hl = sHTS_l[wv];
    const int rb = lane * 8;                                  // fragment read base
    const int wb = (g >> 1) * 128 + m * 8 + (g & 1) * 4;      // phase write base
    const float2* __restrict__ g2 = (const float2*)grid;

    for (int pt = 0; pt < 16; ++pt) {
        const int p = blockIdx.x * 2048 + wv * 256 + pt * 16 + m;
        const int pc = (p < N) ? p : (N - 1);

        const float px = pos[3 * pc + 0];
        const float py = pos[3 * pc + 1];
        const float pz = pos[3 * pc + 2];

        // ---- trilerp forward (redundant across g: every lane has point m's data) ----
        const float ux = (px + 1.f) * 7.5f;
        const float uy = (py + 1.f) * 7.5f;
        const float uz = (pz + 1.f) * 7.5f;
        int ix = (int)floorf(ux); ix = ix < 0 ? 0 : (ix > RR - 2 ? RR - 2 : ix);
        int iy = (int)floorf(uy); iy = iy < 0 ? 0 : (iy > RR - 2 ? RR - 2 : iy);
        int iz = (int)floorf(uz); iz = iz < 0 ? 0 : (iz > RR - 2 ? RR - 2 : iz);
        const float fx = ux - (float)ix;
        const float fy = uy - (float)iy;
        const float fz = uz - (float)iz;
        const int cbase = (ix * RR + iy) * RR + iz;
        const float wx0 = 1.f - fx, wx1 = fx;
        const float wy0 = 1.f - fy, wy1 = fy;
        const float wz0 = 1.f - fz, wz1 = fz;
        float e0, e1;
        {
            const float2 c000 = g2[cbase];
            const float2 c001 = g2[cbase + 1];
            const float2 c010 = g2[cbase + RR];
            const float2 c011 = g2[cbase + RR + 1];
            const float2 c100 = g2[cbase + RR * RR];
            const float2 c101 = g2[cbase + RR * RR + 1];
            const float2 c110 = g2[cbase + RR * RR + RR];
            const float2 c111 = g2[cbase + RR * RR + RR + 1];
            const float w000 = wx0 * wy0 * wz0, w001 = wx0 * wy0 * wz1;
            const float w010 = wx0 * wy1 * wz0, w011 = wx0 * wy1 * wz1;
            const float w100 = wx1 * wy0 * wz0, w101 = wx1 * wy0 * wz1;
            const float w110 = wx1 * wy1 * wz0, w111 = wx1 * wy1 * wz1;
            e0 = w000 * c000.x + w001 * c001.x + w010 * c010.x + w011 * c011.x
               + w100 * c100.x + w101 * c101.x + w110 * c110.x + w111 * c111.x;
            e1 = w000 * c000.y + w001 * c001.y + w010 * c010.y + w011 * c011.y
               + w100 * c100.y + w101 * c101.y + w110 * c110.y + w111 * c111.y;
        }

        // ---- x row built IN REGISTERS (no LDS round-trip) ----
        bf16x8 xbh, xbl;
        {
            const float xv[6] = {e0, e1, px, py, pz, 1.f};
            #pragma unroll
            for (int e = 0; e < 6; ++e) {
                const unsigned short hs = f2bf(xv[e]);
                xbh[e] = (short)hs;
                xbl[e] = (short)f2bf(xv[e] - bf2f(hs));
            }
            xbh[6] = 0; xbh[7] = 0; xbl[6] = 0; xbl[7] = 0;
        }

        // ---- G0: z1^T[j][p], rows j = jt*16+4g+r ----
        f32x4 c0[8];
        #pragma unroll
        for (int jt = 0; jt < 8; ++jt) {
            const bf16x8 ah = *(const bf16x8*)&sW1T_h[jt * 512 + rb];
            const bf16x8 al = *(const bf16x8*)&sW1T_l[jt * 512 + rb];
            f32x4 c = {0.f, 0.f, 0.f, 0.f};
            c = MFMA16(ah, xbh, c);
            c = MFMA16(ah, xbl, c);
            c = MFMA16(al, xbh, c);
            c0[jt] = c;
        }

        // ---- h = sin(30*z1) -> hts (hi/lo) ----
        #pragma unroll
        for (int jt = 0; jt < 8; ++jt) {
            short4v h4, l4;
            #pragma unroll
            for (int r = 0; r < 4; ++r) {
                const float h = __sinf(30.f * c0[jt][r]);
                const unsigned short hs = f2bf(h);
                h4[r] = (short)hs;
                l4[r] = (short)f2bf(h - bf2f(hs));
            }
            *(short4v*)&hh[wb + jt * 256] = h4;
            *(short4v*)&hl[wb + jt * 256] = l4;
        }

        // ---- G1: z2^T[i][p] = W2T(hi) x h(hi/lo) ----
        f32x4 c1[8];
        #pragma unroll
        for (int it = 0; it < 8; ++it) c1[it] = (f32x4){0.f, 0.f, 0.f, 0.f};
        #pragma unroll
        for (int ks = 0; ks < 4; ++ks) {
            const bf16x8 bh = *(const bf16x8*)&hh[ks * 512 + rb];
            const bf16x8 bl = *(const bf16x8*)&hl[ks * 512 + rb];
            #pragma unroll
            for (int it = 0; it < 8; ++it) {
                const bf16x8 a = *(const bf16x8*)&sW2T[it * 2048 + ks * 512 + rb];
                c1[it] = MFMA16(a, bh, c1[it]);
                c1[it] = MFMA16(a, bl, c1[it]);
            }
        }

        // ---- phase 2: sdf partial + t = W3*cos(z2) -> hts ----
        float sdfp = 0.f;
        #pragma unroll
        for (int it = 0; it < 8; ++it) {
            const f32x4 b2v = *(const f32x4*)&sb2[it * 16 + 4 * g];
            const f32x4 w3v = *(const f32x4*)&sW3[it * 16 + 4 * g];
            short4v h4, l4;
            #pragma unroll
            for (int r = 0; r < 4; ++r) {
                const float z2 = c1[it][r] + b2v[r];
                const float s2 = __sinf(z2);
                const float cc = __cosf(z2);
                sdfp = fmaf(w3v[r], s2, sdfp);
                const float t = w3v[r] * cc;
                const unsigned short hs = f2bf(t);
                h4[r] = (short)hs;
                l4[r] = (short)f2bf(t - bf2f(hs));
            }
            *(short4v*)&hh[wb + it * 256] = h4;
            *(short4v*)&hl[wb + it * 256] = l4;
        }
        sdfp += __shfl_xor(sdfp, 16);
        sdfp += __shfl_xor(sdfp, 32);
        const float sdf = b3v + sdfp;

        // ---- G2: u^T[j][p] = W2N(hi) x t(hi/lo) ----
        f32x4 c2[8];
        #pragma unroll
        for (int jt = 0; jt < 8; ++jt) c2[jt] = (f32x4){0.f, 0.f, 0.f, 0.f};
        #pragma unroll
        for (int ks = 0; ks < 4; ++ks) {
            const bf16x8 bh = *(const bf16x8*)&hh[ks * 512 + rb];
            const bf16x8 bl = *(const bf16x8*)&hl[ks * 512 + rb];
            #pragma unroll
            for (int jt = 0; jt < 8; ++jt) {
                const bf16x8 a = *(const bf16x8*)&sW2N[jt * 2048 + ks * 512 + rb];
                c2[jt] = MFMA16(a, bh, c2[jt]);
                c2[jt] = MFMA16(a, bl, c2[jt]);
            }
        }

        // ---- phase 3: s_j = u_j * 30 * cos(30*z1_j) -> hts ----
        #pragma unroll
        for (int jt = 0; jt < 8; ++jt) {
            short4v h4, l4;
            #pragma unroll
            for (int r = 0; r < 4; ++r) {
                const float sj = c2[jt][r] * 30.f * __cosf(30.f * c0[jt][r]);
                const unsigned short hs = f2bf(sj);
                h4[r] = (short)hs;
                l4[r] = (short)f2bf(sj - bf2f(hs));
            }
            *(short4v*)&hh[wb + jt * 256] = h4;
            *(short4v*)&hl[wb + jt * 256] = l4;
        }

        // ---- G3: dx[k][p] = W1B(hi/lo) x s(hi/lo) ----
        f32x4 c3 = {0.f, 0.f, 0.f, 0.f};
        #pragma unroll
        for (int ks = 0; ks < 4; ++ks) {
            const bf16x8 bh = *(const bf16x8*)&hh[ks * 512 + rb];
            const bf16x8 bl = *(const bf16x8*)&hl[ks * 512 + rb];
            const bf16x8 ah = *(const bf16x8*)&sW1B_h[ks * 512 + rb];
            const bf16x8 al = *(const bf16x8*)&sW1B_l[ks * 512 + rb];
            c3 = MFMA16(ah, bh, c3);
            c3 = MFMA16(ah, bl, c3);
            c3 = MFMA16(al, bh, c3);
        }
        // lane m needs k=4 (dz) which lives in lane m+16, reg 0
        const float d4v = __shfl(c3[0], (lane & 15) + 16);

        // ---- outputs (lanes 0..15 hold k=0..3 in c3[0..3]) ----
        if (lane < 16 && p < N) {
            const float de0 = c3[0], de1 = c3[1];
            float gx, gy, gz;
            {
                const float2 r000 = g2[cbase];
                const float2 r001 = g2[cbase + 1];
                const float2 r010 = g2[cbase + RR];
                const float2 r011 = g2[cbase + RR + 1];
                const float2 r100 = g2[cbase + RR * RR];
                const float2 r101 = g2[cbase + RR * RR + 1];
                const float2 r110 = g2[cbase + RR * RR + RR];
                const float2 r111 = g2[cbase + RR * RR + RR + 1];
                const float q000 = r000.x * de0 + r000.y * de1;
                const float q001 = r001.x * de0 + r001.y * de1;
                const float q010 = r010.x * de0 + r010.y * de1;
                const float q011 = r011.x * de0 + r011.y * de1;
                const float q100 = r100.x * de0 + r100.y * de1;
                const float q101 = r101.x * de0 + r101.y * de1;
                const float q110 = r110.x * de0 + r110.y * de1;
                const float q111 = r111.x * de0 + r111.y * de1;
                gx = 7.5f * (wy0 * wz0 * (q100 - q000) + wy0 * wz1 * (q101 - q001)
                           + wy1 * wz0 * (q110 - q010) + wy1 * wz1 * (q111 - q011));
                gy = 7.5f * (wx0 * wz0 * (q010 - q000) + wx0 * wz1 * (q011 - q001)
                           + wx1 * wz0 * (q110 - q100) + wx1 * wz1 * (q111 - q101));
                gz = 7.5f * (wx0 * wy0 * (q001 - q000) + wx0 * wy1 * (q011 - q010)
                           + wx1 * wy0 * (q101 - q100) + wx1 * wy1 * (q111 - q110));
            }
            const bool msk = (px >= -1.f) && (px <= 1.f) && (py >= -1.f) && (py <= 1.f)
                          && (pz >= -1.f) && (pz <= 1.f);
            out[p] = sdf;
            out[N + 3 * p + 0] = c3[2] + gx;
            out[N + 3 * p + 1] = c3[3] + gy;
            out[N + 3 * p + 2] = d4v + gz;
            out[4 * N + p] = msk ? 1.f : 0.f;
        }
    }
}

extern "C" void kernel_launch(void* const* d_in, const int* in_sizes, int n_in,
                              void* d_out, int out_size, void* d_ws, size_t ws_size,
                              hipStream_t stream) {
    const float* pos  = (const float*)d_in[0];
    const float* grid = (const float*)d_in[1];
    const float* W1   = (const float*)d_in[2];
    const float* b1   = (const float*)d_in[3];
    const float* W2   = (const float*)d_in[4];
    const float* b2   = (const float*)d_in[5];
    const float* W3   = (const float*)d_in[6];
    const float* b3   = (const float*)d_in[7];
    float* out = (float*)d_out;
    const int N = in_sizes[0] / 3;
    const int blocks = (N + 2047) / 2048;
    hipLaunchKernelGGL(siren_mfma, dim3(blocks), dim3(512), 0, stream,
                       pos, grid, W1, b1, W2, b2, W3, b3, out, N);
}

// Round 8
// 238.025 us; speedup vs baseline: 24.9070x; 1.0145x over previous
//
#include <hip/hip_runtime.h>
#include <hip/hip_bf16.h>
#include <math.h>

#define RR 16

typedef __attribute__((ext_vector_type(8))) short bf16x8;
typedef __attribute__((ext_vector_type(4))) float f32x4;

#define MFMA16(a, b, c) __builtin_amdgcn_mfma_f32_16x16x32_bf16((a), (b), (c), 0, 0, 0)

static __device__ __forceinline__ unsigned short f2bf(float f) {   // staging only
    union { float f; unsigned u; } v; v.f = f;
    unsigned r = v.u + 0x7fffu + ((v.u >> 16) & 1u);
    return (unsigned short)(r >> 16);
}
static __device__ __forceinline__ float bf2f(unsigned short h) {
    union { float f; unsigned u; } v; v.u = ((unsigned)h) << 16; return v.f;
}

// packed f32->bf16 hi/lo split, NO inline asm: the compiler owns instruction
// selection (v_cvt_pk_bf16_f32 where profitable) and all scheduling/hazards.
static __device__ __forceinline__ void pk4(float a, float b, float c, float d,
                                           uint2* hi, uint2* lo) {
    union { __hip_bfloat162 b; unsigned u; } H01, H23, L01, L23;
    H01.b = __float22bfloat162_rn(float2{a, b});   // lo16 = bf16(a), hi16 = bf16(b)
    H23.b = __float22bfloat162_rn(float2{c, d});
    const float r0 = __uint_as_float(H01.u << 16);
    const float r1 = __uint_as_float(H01.u & 0xffff0000u);
    const float r2 = __uint_as_float(H23.u << 16);
    const float r3 = __uint_as_float(H23.u & 0xffff0000u);
    L01.b = __float22bfloat162_rn(float2{a - r0, b - r1});
    L23.b = __float22bfloat162_rn(float2{c - r2, d - r3});
    hi->x = H01.u; hi->y = H23.u;
    lo->x = L01.u; lo->y = L23.u;
}

__global__ __launch_bounds__(512, 2)
void siren_mfma(const float* __restrict__ pos, const float* __restrict__ grid,
                const float* __restrict__ W1, const float* __restrict__ b1,
                const float* __restrict__ W2, const float* __restrict__ b2,
                const float* __restrict__ W3, const float* __restrict__ b3,
                float* __restrict__ out, int N)
{
    // ---- LDS: 156,672 B ----
    __shared__ short sW2T[128 * 128];    // A of G1: (i=it*16+m, j=ks*32+8g+e), hi only
    __shared__ short sW2N[128 * 128];    // A of G2: (j=jt*16+m, i=ks*32+8g+e), hi only
    __shared__ short sW1T_h[128 * 32];   // A of G0: (j=jt*16+m, k=8g+e) k<5=W1,k==5=b1
    __shared__ short sW1T_l[128 * 32];
    __shared__ short sW1B_h[16 * 128];   // A of G3: (k=m, j=ks*32+8g+e), 30*W1, else 0
    __shared__ short sW1B_l[16 * 128];
    __shared__ float sb2[128];
    __shared__ float sW3[128];
    __shared__ short sHTS_h[8][16 * 128]; // per-wave [point m][feature] h -> t -> s
    __shared__ short sHTS_l[8][16 * 128];

    const int tid = threadIdx.x;

    // ================= weight staging (once per block, 512 threads) =================
    {   // W2T: thread (i = tid&127, ks = tid>>7) covers j = ks*32 .. +31
        const int i = tid & 127, ks = tid >> 7;
        const int base = ((i >> 4) * 2048) + ks * 512 + (i & 15) * 8;
        #pragma unroll
        for (int g = 0; g < 4; ++g) {
            bf16x8 h8;
            #pragma unroll
            for (int e = 0; e < 8; ++e)
                h8[e] = (short)f2bf(W2[(ks * 32 + g * 8 + e) * 128 + i]);
            *(bf16x8*)&sW2T[base + g * 128] = h8;
        }
    }
    {   // W2N: thread (j = tid&127, ks = tid>>7) covers i = ks*32 .. +31 (contiguous)
        const int j = tid & 127, ks = tid >> 7;
        const int base = ((j >> 4) * 2048) + ks * 512 + (j & 15) * 8;
        const float4* __restrict__ w4 = (const float4*)&W2[j * 128 + ks * 32];
        #pragma unroll
        for (int g = 0; g < 4; ++g) {
            const float4 a = w4[g * 2];
            const float4 b = w4[g * 2 + 1];
            bf16x8 h8;
            h8[0] = (short)f2bf(a.x); h8[1] = (short)f2bf(a.y);
            h8[2] = (short)f2bf(a.z); h8[3] = (short)f2bf(a.w);
            h8[4] = (short)f2bf(b.x); h8[5] = (short)f2bf(b.y);
            h8[6] = (short)f2bf(b.z); h8[7] = (short)f2bf(b.w);
            *(bf16x8*)&sW2N[base + g * 128] = h8;
        }
    }
    if (tid < 128) {   // W1T hi/lo (+ zero padding of k>=6)
        const int j = tid;
        const int base = ((j >> 4) * 512) + (j & 15) * 8;
        bf16x8 h8, l8;
        #pragma unroll
        for (int e = 0; e < 8; ++e) {
            const float v = (e < 5) ? W1[e * 128 + j] : (e == 5 ? b1[j] : 0.f);
            const unsigned short hs = f2bf(v);
            h8[e] = (short)hs;
            l8[e] = (short)f2bf(v - bf2f(hs));
        }
        *(bf16x8*)&sW1T_h[base] = h8;
        *(bf16x8*)&sW1T_l[base] = l8;
        bf16x8 z8 = {0, 0, 0, 0, 0, 0, 0, 0};
        #pragma unroll
        for (int g = 1; g < 4; ++g) {
            *(bf16x8*)&sW1T_h[base + g * 128] = z8;
            *(bf16x8*)&sW1T_l[base + g * 128] = z8;
        }
        sb2[j] = b2[j];
        sW3[j] = W3[j];
    }
    if (tid < 256) {   // W1B hi/lo, PRE-SCALED by 30 (folds bwd chain factor)
        const int k = tid & 15, gg = (tid >> 4) & 3, ks = tid >> 6;
        const int base = ks * 512 + gg * 128 + k * 8;
        bf16x8 h8, l8;
        #pragma unroll
        for (int e = 0; e < 8; ++e) {
            const int j = ks * 32 + gg * 8 + e;
            const float v = (k < 5) ? 30.f * W1[k * 128 + j] : 0.f;
            const unsigned short hs = f2bf(v);
            h8[e] = (short)hs;
            l8[e] = (short)f2bf(v - bf2f(hs));
        }
        *(bf16x8*)&sW1B_h[base] = h8;
        *(bf16x8*)&sW1B_l[base] = l8;
    }
    const float b3v = b3[0];
    __syncthreads();

    // ================= main loop: 16 point-tiles of 16 per wave =================
    const int lane = tid & 63;
    const int wv = tid >> 6;
    const int g = lane >> 4;
    const int m = lane & 15;

    char* __restrict__ hhB = (char*)sHTS_h[wv];
    char* __restrict__ hlB = (char*)sHTS_l[wv];
    const int rbB = lane * 16;                                     // byte read base
    const int wbB = (g >> 1) * 256 + m * 16 + (g & 1) * 8;         // byte write base
    const int rbS = lane * 8;                                      // short idx (weights)
    const float2* __restrict__ g2 = (const float2*)grid;

    #pragma unroll 1
    for (int pt = 0; pt < 16; ++pt) {
        const int p = blockIdx.x * 2048 + wv * 256 + pt * 16 + m;
        const int pc = (p < N) ? p : (N - 1);

        const float px = pos[3 * pc + 0];
        const float py = pos[3 * pc + 1];
        const float pz = pos[3 * pc + 2];

        // ---- trilerp forward (redundant across g: every lane has point m's data) ----
        const float ux = (px + 1.f) * 7.5f;
        const float uy = (py + 1.f) * 7.5f;
        const float uz = (pz + 1.f) * 7.5f;
        int ix = (int)floorf(ux); ix = ix < 0 ? 0 : (ix > RR - 2 ? RR - 2 : ix);
        int iy = (int)floorf(uy); iy = iy < 0 ? 0 : (iy > RR - 2 ? RR - 2 : iy);
        int iz = (int)floorf(uz); iz = iz < 0 ? 0 : (iz > RR - 2 ? RR - 2 : iz);
        const float fx = ux - (float)ix;
        const float fy = uy - (float)iy;
        const float fz = uz - (float)iz;
        const int cbase = (ix * RR + iy) * RR + iz;
        const float wx0 = 1.f - fx, wx1 = fx;
        const float wy0 = 1.f - fy, wy1 = fy;
        const float wz0 = 1.f - fz, wz1 = fz;
        float e0, e1;
        {
            const float2 c000 = g2[cbase];
            const float2 c001 = g2[cbase + 1];
            const float2 c010 = g2[cbase + RR];
            const float2 c011 = g2[cbase + RR + 1];
            const float2 c100 = g2[cbase + RR * RR];
            const float2 c101 = g2[cbase + RR * RR + 1];
            const float2 c110 = g2[cbase + RR * RR + RR];
            const float2 c111 = g2[cbase + RR * RR + RR + 1];
            const float w000 = wx0 * wy0 * wz0, w001 = wx0 * wy0 * wz1;
            const float w010 = wx0 * wy1 * wz0, w011 = wx0 * wy1 * wz1;
            const float w100 = wx1 * wy0 * wz0, w101 = wx1 * wy0 * wz1;
            const float w110 = wx1 * wy1 * wz0, w111 = wx1 * wy1 * wz1;
            e0 = w000 * c000.x + w001 * c001.x + w010 * c010.x + w011 * c011.x
               + w100 * c100.x + w101 * c101.x + w110 * c110.x + w111 * c111.x;
            e1 = w000 * c000.y + w001 * c001.y + w010 * c010.y + w011 * c011.y
               + w100 * c100.y + w101 * c101.y + w110 * c110.y + w111 * c111.y;
        }

        // ---- x row built IN REGISTERS via packed conversion ----
        bf16x8 xbh, xbl;
        {
            union { bf16x8 v; uint2 u[2]; } XH, XL;
            pk4(e0, e1, px, py, &XH.u[0], &XL.u[0]);
            pk4(pz, 1.f, 0.f, 0.f, &XH.u[1], &XL.u[1]);
            xbh = XH.v; xbl = XL.v;
        }

        // ---- G0: z1^T[j][p], rows j = jt*16+4g+r ----
        f32x4 c0[8];
        #pragma unroll
        for (int jt = 0; jt < 8; ++jt) {
            const bf16x8 ah = *(const bf16x8*)&sW1T_h[jt * 512 + rbS];
            const bf16x8 al = *(const bf16x8*)&sW1T_l[jt * 512 + rbS];
            f32x4 c = {0.f, 0.f, 0.f, 0.f};
            c = MFMA16(ah, xbh, c);
            c = MFMA16(ah, xbl, c);
            c = MFMA16(al, xbh, c);
            c0[jt] = c;
        }

        // ---- h = sin(30*z1) -> hts (hi/lo) ----
        #pragma unroll
        for (int jt = 0; jt < 8; ++jt) {
            const float a0 = __sinf(30.f * c0[jt][0]);
            const float a1 = __sinf(30.f * c0[jt][1]);
            const float a2 = __sinf(30.f * c0[jt][2]);
            const float a3 = __sinf(30.f * c0[jt][3]);
            uint2 hi, lo;
            pk4(a0, a1, a2, a3, &hi, &lo);
            *(uint2*)(hhB + wbB + jt * 512) = hi;
            *(uint2*)(hlB + wbB + jt * 512) = lo;
        }

        // ---- G1: z2^T[i][p] = W2T(hi) x h(hi/lo), acc seeded with b2 ----
        f32x4 c1[8];
        #pragma unroll
        for (int it = 0; it < 8; ++it) c1[it] = *(const f32x4*)&sb2[it * 16 + 4 * g];
        __builtin_amdgcn_s_setprio(1);
        #pragma unroll
        for (int ks = 0; ks < 4; ++ks) {
            const bf16x8 bh = *(const bf16x8*)(hhB + ks * 1024 + rbB);
            const bf16x8 bl = *(const bf16x8*)(hlB + ks * 1024 + rbB);
            #pragma unroll
            for (int it = 0; it < 8; ++it) {
                const bf16x8 a = *(const bf16x8*)&sW2T[it * 2048 + ks * 512 + rbS];
                c1[it] = MFMA16(a, bh, c1[it]);
                c1[it] = MFMA16(a, bl, c1[it]);
            }
        }
        __builtin_amdgcn_s_setprio(0);

        // ---- phase 2: sdf partial + t = W3*cos(z2) -> hts (one reduction/pair) ----
        float sdfp = 0.f;
        #pragma unroll
        for (int it = 0; it < 8; ++it) {
            const f32x4 w3v = *(const f32x4*)&sW3[it * 16 + 4 * g];
            float s0, cc0, s1, cc1, s2, cc2, s3, cc3;
            __sincosf(c1[it][0], &s0, &cc0);
            __sincosf(c1[it][1], &s1, &cc1);
            __sincosf(c1[it][2], &s2, &cc2);
            __sincosf(c1[it][3], &s3, &cc3);
            sdfp = fmaf(w3v[0], s0, sdfp);
            sdfp = fmaf(w3v[1], s1, sdfp);
            sdfp = fmaf(w3v[2], s2, sdfp);
            sdfp = fmaf(w3v[3], s3, sdfp);
            uint2 hi, lo;
            pk4(w3v[0] * cc0, w3v[1] * cc1, w3v[2] * cc2, w3v[3] * cc3, &hi, &lo);
            *(uint2*)(hhB + wbB + it * 512) = hi;
            *(uint2*)(hlB + wbB + it * 512) = lo;
        }
        sdfp += __shfl_xor(sdfp, 16);
        sdfp += __shfl_xor(sdfp, 32);
        const float sdf = b3v + sdfp;

        // ---- G2: u^T[j][p] = W2N(hi) x t(hi/lo) ----
        f32x4 c2[8];
        #pragma unroll
        for (int jt = 0; jt < 8; ++jt) c2[jt] = (f32x4){0.f, 0.f, 0.f, 0.f};
        __builtin_amdgcn_s_setprio(1);
        #pragma unroll
        for (int ks = 0; ks < 4; ++ks) {
            const bf16x8 bh = *(const bf16x8*)(hhB + ks * 1024 + rbB);
            const bf16x8 bl = *(const bf16x8*)(hlB + ks * 1024 + rbB);
            #pragma unroll
            for (int jt = 0; jt < 8; ++jt) {
                const bf16x8 a = *(const bf16x8*)&sW2N[jt * 2048 + ks * 512 + rbS];
                c2[jt] = MFMA16(a, bh, c2[jt]);
                c2[jt] = MFMA16(a, bl, c2[jt]);
            }
        }
        __builtin_amdgcn_s_setprio(0);

        // ---- phase 3: s_j = u_j * cos(30*z1_j)  (x30 folded into W1B) -> hts ----
        #pragma unroll
        for (int jt = 0; jt < 8; ++jt) {
            const float s0 = c2[jt][0] * __cosf(30.f * c0[jt][0]);
            const float s1 = c2[jt][1] * __cosf(30.f * c0[jt][1]);
            const float s2 = c2[jt][2] * __cosf(30.f * c0[jt][2]);
            const float s3 = c2[jt][3] * __cosf(30.f * c0[jt][3]);
            uint2 hi, lo;
            pk4(s0, s1, s2, s3, &hi, &lo);
            *(uint2*)(hhB + wbB + jt * 512) = hi;
            *(uint2*)(hlB + wbB + jt * 512) = lo;
        }

        // ---- G3: dx[k][p] = (30*W1B)(hi/lo) x s(hi/lo) ----
        f32x4 c3 = {0.f, 0.f, 0.f, 0.f};
        __builtin_amdgcn_s_setprio(1);
        #pragma unroll
        for (int ks = 0; ks < 4; ++ks) {
            const bf16x8 bh = *(const bf16x8*)(hhB + ks * 1024 + rbB);
            const bf16x8 bl = *(const bf16x8*)(hlB + ks * 1024 + rbB);
            const bf16x8 ah = *(const bf16x8*)&sW1B_h[ks * 512 + rbS];
            const bf16x8 al = *(const bf16x8*)&sW1B_l[ks * 512 + rbS];
            c3 = MFMA16(ah, bh, c3);
            c3 = MFMA16(ah, bl, c3);
            c3 = MFMA16(al, bh, c3);
        }
        __builtin_amdgcn_s_setprio(0);
        // lane m needs k=4 (dz) which lives in lane m+16, reg 0
        const float d4v = __shfl(c3[0], (lane & 15) + 16);

        // ---- outputs (lanes 0..15 hold k=0..3 in c3[0..3]) ----
        if (lane < 16 && p < N) {
            const float de0 = c3[0], de1 = c3[1];
            float gx, gy, gz;
            {
                const float2 r000 = g2[cbase];
                const float2 r001 = g2[cbase + 1];
                const float2 r010 = g2[cbase + RR];
                const float2 r011 = g2[cbase + RR + 1];
                const float2 r100 = g2[cbase + RR * RR];
                const float2 r101 = g2[cbase + RR * RR + 1];
                const float2 r110 = g2[cbase + RR * RR + RR];
                const float2 r111 = g2[cbase + RR * RR + RR + 1];
                const float q000 = r000.x * de0 + r000.y * de1;
                const float q001 = r001.x * de0 + r001.y * de1;
                const float q010 = r010.x * de0 + r010.y * de1;
                const float q011 = r011.x * de0 + r011.y * de1;
                const float q100 = r100.x * de0 + r100.y * de1;
                const float q101 = r101.x * de0 + r101.y * de1;
                const float q110 = r110.x * de0 + r110.y * de1;
                const float q111 = r111.x * de0 + r111.y * de1;
                gx = 7.5f * (wy0 * wz0 * (q100 - q000) + wy0 * wz1 * (q101 - q001)
                           + wy1 * wz0 * (q110 - q010) + wy1 * wz1 * (q111 - q011));
                gy = 7.5f * (wx0 * wz0 * (q010 - q000) + wx0 * wz1 * (q011 - q001)
                           + wx1 * wz0 * (q110 - q100) + wx1 * wz1 * (q111 - q101));
                gz = 7.5f * (wx0 * wy0 * (q001 - q000) + wx0 * wy1 * (q011 - q010)
                           + wx1 * wy0 * (q101 - q100) + wx1 * wy1 * (q111 - q110));
            }
            const bool msk = (px >= -1.f) && (px <= 1.f) && (py >= -1.f) && (py <= 1.f)
                          && (pz >= -1.f) && (pz <= 1.f);
            out[p] = sdf;
            out[N + 3 * p + 0] = c3[2] + gx;
            out[N + 3 * p + 1] = c3[3] + gy;
            out[N + 3 * p + 2] = d4v + gz;
            out[4 * N + p] = msk ? 1.f : 0.f;
        }
    }
}

extern "C" void kernel_launch(void* const* d_in, const int* in_sizes, int n_in,
                              void* d_out, int out_size, void* d_ws, size_t ws_size,
                              hipStream_t stream) {
    const float* pos  = (const float*)d_in[0];
    const float* grid = (const float*)d_in[1];
    const float* W1   = (const float*)d_in[2];
    const float* b1   = (const float*)d_in[3];
    const float* W2   = (const float*)d_in[4];
    const float* b2   = (const float*)d_in[5];
    const float* W3   = (const float*)d_in[6];
    const float* b3   = (const float*)d_in[7];
    float* out = (float*)d_out;
    const int N = in_sizes[0] / 3;
    const int blocks = (N + 2047) / 2048;
    hipLaunchKernelGGL(siren_mfma, dim3(blocks), dim3(512), 0, stream,
                       pos, grid, W1, b1, W2, b2, W3, b3, out, N);
}